// Round 2
// baseline (2078.327 us; speedup 1.0000x reference)
//
#include <hip/hip_runtime.h>

typedef unsigned short ush;
typedef __attribute__((ext_vector_type(8))) __bf16 bf16x8;
typedef __attribute__((ext_vector_type(4))) float f32x4;

#define NE 33554432L  // 4*128*128*512 elements per Q/K/V matrix

// ---------- bf16 <-> fp32 helpers (RNE) ----------
__device__ __forceinline__ float b2f(ush u) {
  return __uint_as_float(((unsigned int)u) << 16);
}
__device__ __forceinline__ ush f2b(float f) {
  unsigned int x = __float_as_uint(f);
  x += 0x7fffu + ((x >> 16) & 1u);
  return (ush)(x >> 16);
}

// 4-element load as fp32 from either storage type
__device__ __forceinline__ float4 ld4f(const float* p) { return *(const float4*)p; }
__device__ __forceinline__ float4 ld4f(const ush* p) {
  ushort4 u = *(const ushort4*)p;
  return make_float4(b2f(u.x), b2f(u.y), b2f(u.z), b2f(u.w));
}
__device__ __forceinline__ void st1(float* p, float v) { *p = v; }
__device__ __forceinline__ void st1(ush* p, float v)   { *p = f2b(v); }

// ---------- kernel: input dtype sniffer ----------
// flag[0] = 1 if inputs are bf16, 0 if fp32. Reads only 32KB of x (safe in
// both interpretations). bf16 data: ~100% of ushorts have a plausible bf16
// exponent; fp32-as-ushort: low mantissa halves are uniform junk -> ~58%.
__global__ __launch_bounds__(256)
void detect_dtype(const ush* __restrict__ x, int* __restrict__ flag) {
  __shared__ int red[256];
  const int t = threadIdx.x;
  int cnt = 0;
  for (int i = t; i < 16384; i += 256) {
    const int e = (x[i] >> 7) & 0xFF;
    cnt += (e == 0 || (e >= 100 && e <= 142)) ? 1 : 0;
  }
  red[t] = cnt;
  __syncthreads();
  for (int s = 128; s > 0; s >>= 1) {
    if (t < s) red[t] += red[t + s];
    __syncthreads();
  }
  if (t == 0) flag[0] = (red[0] >= 13107) ? 1 : 0;  // 80% of 16384
}

// ---------- kernel: pack x -> bf16 ----------
__global__ __launch_bounds__(256)
void pack_x(const void* __restrict__ xin, ush* __restrict__ xb,
            const int* __restrict__ flag) {
  const long i0 = ((long)blockIdx.x * 256 + threadIdx.x) * 8;
  if (*flag) {
    *(int4*)&xb[i0] = *(const int4*)&((const ush*)xin)[i0];
  } else {
    const float* xf = (const float*)xin;
    const float4 a = *(const float4*)&xf[i0];
    const float4 b = *(const float4*)&xf[i0 + 4];
    union { ush u[8]; int4 v; } r;
    r.u[0] = f2b(a.x); r.u[1] = f2b(a.y); r.u[2] = f2b(a.z); r.u[3] = f2b(a.w);
    r.u[4] = f2b(b.x); r.u[5] = f2b(b.y); r.u[6] = f2b(b.z); r.u[7] = f2b(b.w);
    *(int4*)&xb[i0] = r.v;
  }
}

// ---------- kernel: pack+transpose weights -> bf16 wT[n][k] = w[k][n] ----------
__global__ __launch_bounds__(256)
void pack_w(const void* __restrict__ w0, const void* __restrict__ w1,
            const void* __restrict__ w2, ush* __restrict__ wTb,
            const int* __restrict__ flag) {
  __shared__ ush tile[32][33];
  const void* w = (blockIdx.z == 0) ? w0 : ((blockIdx.z == 1) ? w1 : w2);
  ush* wT = wTb + (long)blockIdx.z * 262144;
  const int bx = blockIdx.x * 32, by = blockIdx.y * 32;
  const int tx = threadIdx.x & 31, ty = threadIdx.x >> 5;  // ty in 0..7
  const int f = *flag;
#pragma unroll
  for (int j = 0; j < 32; j += 8) {
    const int k = by + ty + j, n = bx + tx;
    tile[ty + j][tx] = f ? ((const ush*)w)[k * 512 + n]
                         : f2b(((const float*)w)[k * 512 + n]);
  }
  __syncthreads();
#pragma unroll
  for (int j = 0; j < 32; j += 8)
    wT[(bx + ty + j) * 512 + by + tx] = tile[tx][ty + j];
}

// ---------- kernel: pack biases -> fp32 ----------
__global__ void pack_bias(const void* __restrict__ b0, const void* __restrict__ b1,
                          const void* __restrict__ b2, float* __restrict__ biasf,
                          const int* __restrict__ flag) {
  const void* b = (blockIdx.x == 0) ? b0 : ((blockIdx.x == 1) ? b1 : b2);
  const int n = threadIdx.x;
  const float v = (*flag) ? b2f(((const ush*)b)[n]) : ((const float*)b)[n];
  biasf[blockIdx.x * 512 + n] = v;
}

// ---------- kernel: QKV projection GEMM (bf16 MFMA, fp32 acc) ----------
// C[m][n] = sum_k xb[m][k] * w[k][n] + bias[n]; wTb holds w transposed.
// block tile 128x128, 4 waves, wave tile 64x64 = 4x4 frags of 16x16x32 MFMA.
// A-frag: lane holds A[m0+(l&15)][k0+(l>>4)*8 + j] (8 contiguous bf16)
// B-frag: lane holds B[k0+(l>>4)*8 + j][n0+(l&15)] = wTb[n][k...] contiguous
// D:      D[(l>>4)*4 + r][l&15]   (m89-verified layout)
template<typename ST>
__global__ __launch_bounds__(256)
void proj_gemm(const ush* __restrict__ xb, const ush* __restrict__ wTb,
               const float* __restrict__ biasf, ST* __restrict__ qkv) {
  const int z = blockIdx.z;
  const ush* wt = wTb + (long)z * 262144;
  const float* bias = biasf + z * 512;
  ST* out = qkv + (long)z * NE;

  const int lane = threadIdx.x & 63;
  const int wvid = threadIdx.x >> 6;
  const int wm = wvid & 1, wn = wvid >> 1;
  const int col = lane & 15, quad = lane >> 4;

  const long m0 = (long)blockIdx.y * 128 + wm * 64;
  const int n0 = blockIdx.x * 128 + wn * 64;

  const f32x4 z4 = {0.f, 0.f, 0.f, 0.f};
  f32x4 acc[4][4];
#pragma unroll
  for (int i = 0; i < 4; i++)
#pragma unroll
    for (int j = 0; j < 4; j++) acc[i][j] = z4;

  const ush* ap[4];
  const ush* bp[4];
#pragma unroll
  for (int i = 0; i < 4; i++) ap[i] = xb + (m0 + i * 16 + col) * 512 + quad * 8;
#pragma unroll
  for (int j = 0; j < 4; j++) bp[j] = wt + (long)(n0 + j * 16 + col) * 512 + quad * 8;

  for (int k0 = 0; k0 < 512; k0 += 32) {
    bf16x8 a[4], b[4];
#pragma unroll
    for (int i = 0; i < 4; i++)
      a[i] = __builtin_bit_cast(bf16x8, *(const int4*)(ap[i] + k0));
#pragma unroll
    for (int j = 0; j < 4; j++)
      b[j] = __builtin_bit_cast(bf16x8, *(const int4*)(bp[j] + k0));
#pragma unroll
    for (int i = 0; i < 4; i++)
#pragma unroll
      for (int j = 0; j < 4; j++)
        acc[i][j] = __builtin_amdgcn_mfma_f32_16x16x32_bf16(a[i], b[j], acc[i][j], 0, 0, 0);
  }

#pragma unroll
  for (int j = 0; j < 4; j++) {
    const int n = n0 + j * 16 + col;
    const float bb = bias[n];
#pragma unroll
    for (int i = 0; i < 4; i++) {
      const long row0 = m0 + i * 16 + quad * 4;
#pragma unroll
      for (int r = 0; r < 4; r++)
        st1(out + (row0 + r) * 512 + n, acc[i][j][r] + bb);
    }
  }
}

// ---------- kernels: axial attention passes (fp32 VALU) ----------
// PASS 1 (column): block (b,n,w); rows = H axis; writes xv in-place over V.
// PASS 2 (row):    block (b,n,h); rows = W axis; reads xv from V buffer,
//                  writes final output with channel c = d*8 + n (dtype per flag).
template<int PASS, typename ST>
__global__ __launch_bounds__(256)
void axial_attn(const ST* __restrict__ Qb, const ST* __restrict__ Kb,
                ST* __restrict__ Vb, void* __restrict__ outp,
                const int* __restrict__ flagp) {
  // LDS (floats): Qs[128*64] | Vs[128*64] | Ks[128*65] overlaid later by P[128*128]
  __shared__ float lds[32768];  // 131072 B
  float* Qs = lds;          // stride 64 (broadcast reads only)
  float* Vs = lds + 8192;   // stride 64 (lane-consecutive reads)
  float* Ks = lds + 16384;  // stride 65 (row-per-lane reads, conflict-free)
  float* P  = lds + 16384;  // stride 128, overlays Ks after kreg extraction

  const int flg = *flagp;
  const int b = blockIdx.z, n = blockIdx.y, p = blockIdx.x;
  long base; int stride;
  if (PASS == 1) { base = ((long)b * 16384 + p) * 512 + n * 64; stride = 65536; }
  else           { base = ((long)(b * 128 + p) * 128) * 512 + n * 64; stride = 512; }

  const int t = threadIdx.x;
  {  // phase 0: cooperative slab loads (coalesced, fp32 into LDS)
    const int rl = t >> 4;
    const int c4 = (t & 15) * 4;
#pragma unroll
    for (int it = 0; it < 8; it++) {
      const int i = rl + it * 16;
      const long g = base + (long)i * stride + c4;
      float4 q = ld4f(Qb + g);
      float4 k = ld4f(Kb + g);
      float4 v = ld4f(Vb + g);
      *(float4*)&Qs[i * 64 + c4] = q;
      Ks[i * 65 + c4 + 0] = k.x;
      Ks[i * 65 + c4 + 1] = k.y;
      Ks[i * 65 + c4 + 2] = k.z;
      Ks[i * 65 + c4 + 3] = k.w;
      *(float4*)&Vs[i * 64 + c4] = v;
    }
  }
  __syncthreads();

  const int lane = t & 63;
  const int r0 = (t >> 6) * 32;  // each wave owns 32 score rows

  // K rows -> registers: lane holds full rows `lane` and `lane+64`
  float kA[64], kB[64];
#pragma unroll
  for (int d = 0; d < 64; d++) {
    kA[d] = Ks[lane * 65 + d];
    kB[d] = Ks[(lane + 64) * 65 + d];
  }
  __syncthreads();  // everyone done with Ks before P overlays it

  const float CLIP = 1.0f - 1e-7f;
  for (int r = 0; r < 32; r++) {
    const int row = r0 + r;
    float a0 = 0.f, a1 = 0.f;  // S[row][lane], S[row][lane+64]
#pragma unroll
    for (int d4 = 0; d4 < 64; d4 += 4) {
      const float4 q = *(const float4*)&Qs[row * 64 + d4];  // broadcast
      a0 = fmaf(q.x, kA[d4 + 0], a0); a1 = fmaf(q.x, kB[d4 + 0], a1);
      a0 = fmaf(q.y, kA[d4 + 1], a0); a1 = fmaf(q.y, kB[d4 + 1], a1);
      a0 = fmaf(q.z, kA[d4 + 2], a0); a1 = fmaf(q.z, kB[d4 + 2], a1);
      a0 = fmaf(q.w, kA[d4 + 3], a0); a1 = fmaf(q.w, kB[d4 + 3], a1);
    }
    // faithful chain: clip(+-(1-eps)) -> /sqrt(64) -> softmax -> clip(eps,1-eps)
    a0 = fminf(fmaxf(a0, -CLIP), CLIP) * 0.125f;
    a1 = fminf(fmaxf(a1, -CLIP), CLIP) * 0.125f;
    float e0 = __expf(a0), e1 = __expf(a1);
    float s = e0 + e1;
#pragma unroll
    for (int off = 32; off > 0; off >>= 1) s += __shfl_xor(s, off);
    const float inv = 1.0f / s;
    float p0 = fminf(fmaxf(e0 * inv, 1e-7f), CLIP);
    float p1 = fminf(fmaxf(e1 * inv, 1e-7f), CLIP);
    P[row * 128 + lane] = p0;
    P[row * 128 + lane + 64] = p1;
  }
  __syncthreads();

  // V column -> registers: lane holds Vs[g][lane] for all g (kA/kB now dead)
  float vr[128];
#pragma unroll
  for (int g = 0; g < 128; g++) vr[g] = Vs[g * 64 + lane];

  for (int r = 0; r < 32; r++) {
    const int row = r0 + r;
    float o0 = 0.f, o1 = 0.f, o2 = 0.f, o3 = 0.f;  // 4 chains hide fma latency
#pragma unroll
    for (int g4 = 0; g4 < 128; g4 += 4) {
      const float4 pp = *(const float4*)&P[row * 128 + g4];  // broadcast
      o0 = fmaf(pp.x, vr[g4 + 0], o0);
      o1 = fmaf(pp.y, vr[g4 + 1], o1);
      o2 = fmaf(pp.z, vr[g4 + 2], o2);
      o3 = fmaf(pp.w, vr[g4 + 3], o3);
    }
    const float o = (o0 + o1) + (o2 + o3);
    if (PASS == 1) {
      // xv[b,n,row,w,d=lane] stored in-place at V[b,row,w,n*64+lane]
      st1(Vb + base + (long)row * stride + lane, o);
    } else {
      // out[b, h=p, w=row, c = d*8 + n], dtype per flag
      const long oi = ((long)(b * 128 + p) * 128 + row) * 512 + lane * 8 + n;
      if (flg) ((ush*)outp)[oi] = f2b(o);
      else     ((float*)outp)[oi] = o;
    }
  }
}

// ---------- host ----------
extern "C" void kernel_launch(void* const* d_in, const int* in_sizes, int n_in,
                              void* d_out, int out_size, void* d_ws, size_t ws_size,
                              hipStream_t stream) {
  const void* x  = d_in[0];
  const void* wq = d_in[1];
  const void* bq = d_in[2];
  const void* wk = d_in[3];
  const void* bk = d_in[4];
  const void* wv = d_in[5];
  const void* bv = d_in[6];

  char* ws = (char*)d_ws;
  int*   flag  = (int*)ws;                       // @0, 256 B
  float* biasf = (float*)(ws + 256);             // 3*512 fp32 = 6 KB
  ush*   wTb   = (ush*)(ws + 8192);              // 3*512*512 bf16 = 1.5 MB
  ush*   xb    = (ush*)(ws + 8192 + 1572864);    // 64 MB, @1581056
  char*  qkv   = ws + 8192 + 1572864 + 67108864; // @68689920
  const size_t needA = 68689920UL + 3UL * NE * 4;  // fp32 QKV path, ~450 MiB

  dim3 blk(256);
  detect_dtype<<<1, blk, 0, stream>>>((const ush*)x, flag);
  pack_bias<<<3, 512, 0, stream>>>(bq, bk, bv, biasf, flag);
  pack_w<<<dim3(16, 16, 3), blk, 0, stream>>>(wq, wk, wv, wTb, flag);
  pack_x<<<16384, blk, 0, stream>>>(x, xb, flag);

  dim3 ggrid(4, 512, 3);
  dim3 agrid(128, 8, 4);
  if (ws_size >= needA) {
    float* Q = (float*)qkv;
    float* K = Q + NE;
    float* V = K + NE;
    proj_gemm<float><<<ggrid, blk, 0, stream>>>(xb, wTb, biasf, Q);
    axial_attn<1, float><<<agrid, blk, 0, stream>>>(Q, K, V, d_out, flag);
    axial_attn<2, float><<<agrid, blk, 0, stream>>>(Q, K, V, d_out, flag);
  } else {
    // bf16-storage fallback (~258 MiB): Q/K/V stored bf16, compute stays fp32
    ush* Q = (ush*)qkv;
    ush* K = Q + NE;
    ush* V = K + NE;
    proj_gemm<ush><<<ggrid, blk, 0, stream>>>(xb, wTb, biasf, Q);
    axial_attn<1, ush><<<agrid, blk, 0, stream>>>(Q, K, V, d_out, flag);
    axial_attn<2, ush><<<agrid, blk, 0, stream>>>(Q, K, V, d_out, flag);
  }
}

// Round 3
// 877.731 us; speedup vs baseline: 2.3678x; 2.3678x over previous
//
#include <hip/hip_runtime.h>

typedef unsigned short ush;
typedef __attribute__((ext_vector_type(8))) __bf16 bf16x8;
typedef __attribute__((ext_vector_type(4))) float f32x4;

#define NE 33554432L  // 4*128*128*512 elements per Q/K/V matrix

// ---------- bf16 <-> fp32 helpers (RNE) ----------
__device__ __forceinline__ float b2f(ush u) {
  return __uint_as_float(((unsigned int)u) << 16);
}
__device__ __forceinline__ ush f2b(float f) {
  unsigned int x = __float_as_uint(f);
  x += 0x7fffu + ((x >> 16) & 1u);
  return (ush)(x >> 16);
}
__device__ __forceinline__ bf16x8 bc8(int4 v) { return __builtin_bit_cast(bf16x8, v); }

// ---------- kernel: input dtype sniffer ----------
// flag[0] = 1 if inputs are bf16, 0 if fp32 (fp32-as-ushort exponents are junk).
__global__ __launch_bounds__(256)
void detect_dtype(const ush* __restrict__ x, int* __restrict__ flag) {
  __shared__ int red[256];
  const int t = threadIdx.x;
  int cnt = 0;
  for (int i = t; i < 16384; i += 256) {
    const int e = (x[i] >> 7) & 0xFF;
    cnt += (e == 0 || (e >= 100 && e <= 142)) ? 1 : 0;
  }
  red[t] = cnt;
  __syncthreads();
  for (int s = 128; s > 0; s >>= 1) {
    if (t < s) red[t] += red[t + s];
    __syncthreads();
  }
  if (t == 0) flag[0] = (red[0] >= 13107) ? 1 : 0;  // 80% of 16384
}

// ---------- kernel: pack x -> bf16 ----------
__global__ __launch_bounds__(256)
void pack_x(const void* __restrict__ xin, ush* __restrict__ xb,
            const int* __restrict__ flag) {
  const long i0 = ((long)blockIdx.x * 256 + threadIdx.x) * 8;
  if (*flag) {
    *(int4*)&xb[i0] = *(const int4*)&((const ush*)xin)[i0];
  } else {
    const float* xf = (const float*)xin;
    const float4 a = *(const float4*)&xf[i0];
    const float4 b = *(const float4*)&xf[i0 + 4];
    union { ush u[8]; int4 v; } r;
    r.u[0] = f2b(a.x); r.u[1] = f2b(a.y); r.u[2] = f2b(a.z); r.u[3] = f2b(a.w);
    r.u[4] = f2b(b.x); r.u[5] = f2b(b.y); r.u[6] = f2b(b.z); r.u[7] = f2b(b.w);
    *(int4*)&xb[i0] = r.v;
  }
}

// ---------- kernel: pack+transpose weights -> bf16 wT[n][k] = w[k][n] ----------
__global__ __launch_bounds__(256)
void pack_w(const void* __restrict__ w0, const void* __restrict__ w1,
            const void* __restrict__ w2, ush* __restrict__ wTb,
            const int* __restrict__ flag) {
  __shared__ ush tile[32][33];
  const void* w = (blockIdx.z == 0) ? w0 : ((blockIdx.z == 1) ? w1 : w2);
  ush* wT = wTb + (long)blockIdx.z * 262144;
  const int bx = blockIdx.x * 32, by = blockIdx.y * 32;
  const int tx = threadIdx.x & 31, ty = threadIdx.x >> 5;
  const int f = *flag;
#pragma unroll
  for (int j = 0; j < 32; j += 8) {
    const int k = by + ty + j, n = bx + tx;
    tile[ty + j][tx] = f ? ((const ush*)w)[k * 512 + n]
                         : f2b(((const float*)w)[k * 512 + n]);
  }
  __syncthreads();
#pragma unroll
  for (int j = 0; j < 32; j += 8)
    wT[(bx + ty + j) * 512 + by + tx] = tile[tx][ty + j];
}

// ---------- kernel: pack biases -> fp32 ----------
__global__ void pack_bias(const void* __restrict__ b0, const void* __restrict__ b1,
                          const void* __restrict__ b2, float* __restrict__ biasf,
                          const int* __restrict__ flag) {
  const void* b = (blockIdx.x == 0) ? b0 : ((blockIdx.x == 1) ? b1 : b2);
  const int n = threadIdx.x;
  const float v = (*flag) ? b2f(((const ush*)b)[n]) : ((const float*)b)[n];
  biasf[blockIdx.x * 512 + n] = v;
}

// ---------- kernel: QKV projection GEMM (bf16 MFMA, fp32 acc, bf16 out) ----------
__global__ __launch_bounds__(256)
void proj_gemm(const ush* __restrict__ xb, const ush* __restrict__ wTb,
               const float* __restrict__ biasf, ush* __restrict__ qkv) {
  const int z = blockIdx.z;
  const ush* wt = wTb + (long)z * 262144;
  const float* bias = biasf + z * 512;
  ush* out = qkv + (long)z * NE;

  const int lane = threadIdx.x & 63;
  const int wvid = threadIdx.x >> 6;
  const int wm = wvid & 1, wn = wvid >> 1;
  const int col = lane & 15, quad = lane >> 4;

  const long m0 = (long)blockIdx.y * 128 + wm * 64;
  const int n0 = blockIdx.x * 128 + wn * 64;

  const f32x4 z4 = {0.f, 0.f, 0.f, 0.f};
  f32x4 acc[4][4];
#pragma unroll
  for (int i = 0; i < 4; i++)
#pragma unroll
    for (int j = 0; j < 4; j++) acc[i][j] = z4;

  const ush* ap[4];
  const ush* bp[4];
#pragma unroll
  for (int i = 0; i < 4; i++) ap[i] = xb + (m0 + i * 16 + col) * 512 + quad * 8;
#pragma unroll
  for (int j = 0; j < 4; j++) bp[j] = wt + (long)(n0 + j * 16 + col) * 512 + quad * 8;

  for (int k0 = 0; k0 < 512; k0 += 32) {
    bf16x8 a[4], b[4];
#pragma unroll
    for (int i = 0; i < 4; i++) a[i] = bc8(*(const int4*)(ap[i] + k0));
#pragma unroll
    for (int j = 0; j < 4; j++) b[j] = bc8(*(const int4*)(bp[j] + k0));
#pragma unroll
    for (int i = 0; i < 4; i++)
#pragma unroll
      for (int j = 0; j < 4; j++)
        acc[i][j] = __builtin_amdgcn_mfma_f32_16x16x32_bf16(a[i], b[j], acc[i][j], 0, 0, 0);
  }

#pragma unroll
  for (int j = 0; j < 4; j++) {
    const int n = n0 + j * 16 + col;
    const float bb = bias[n];
#pragma unroll
    for (int i = 0; i < 4; i++) {
      const long row0 = m0 + i * 16 + quad * 4;
#pragma unroll
      for (int r = 0; r < 4; r++)
        out[(row0 + r) * 512 + n] = f2b(acc[i][j][r] + bb);
    }
  }
}

// ---------- MFMA axial attention ----------
// PASS 1 (column): block (b,n,w); rows = H; writes xv in-place over V (bf16).
// PASS 2 (row):    block (b,n,h); rows = W; V buffer holds xv; writes output.
// Per block: S = Q*K^T (128x128x64) -> softmax -> xv = P*V (128x128x128),
// all matmuls on MFMA. LDS 54272 B -> 3 blocks/CU.
#define QS_STRIDE 72    // bf16, 144 B rows (16B aligned), uniform bank groups
#define VT_STRIDE 136   // Vt[d][g], 272 B rows
#define P_STRIDE  136

// XOR swizzle on g-blocks of Vt: breaks the 16-way write conflict (d-block
// coefficient 1088 ush aliases to bank 0 without it), keeps 8-contig g for b128.
__device__ __forceinline__ int vt_idx(int d, int g) {
  return d * VT_STRIDE + ((((g >> 3) ^ ((d >> 3) & 7)) << 3) | (g & 7));
}

template<int PASS>
__global__ __launch_bounds__(256, 3)
void axial_attn_mfma(const ush* __restrict__ Qb, const ush* __restrict__ Kb,
                     ush* __restrict__ Vb, void* __restrict__ outp,
                     const int* __restrict__ flagp) {
  __shared__ ush smem[27136];          // 54272 B
  ush* Qs = smem;                      // [128][72]
  ush* Ks = smem + 9216;               // [128][72]
  ush* Vt = smem + 18432;              // [64][136] swizzled
  ush* P  = smem;                      // [128][136] overlays Qs+Ks after barrier1

  const int flg = *flagp;
  const int b = blockIdx.z, n = blockIdx.y, pp = blockIdx.x;
  long base; int stride;
  if (PASS == 1) { base = ((long)b * 16384 + pp) * 512 + n * 64; stride = 65536; }
  else           { base = ((long)(b * 128 + pp) * 128) * 512 + n * 64; stride = 512; }

  const int t = threadIdx.x;
  // phase 0: stage Q,K row-major; V transposed (swizzled)
#pragma unroll
  for (int it = 0; it < 4; it++) {
    const int c = t + it * 256;
    const int row = c >> 3, c8 = c & 7;
    const long g = base + (long)row * stride + c8 * 8;
    int4 q = *(const int4*)(Qb + g);
    int4 k = *(const int4*)(Kb + g);
    int4 v = *(const int4*)(Vb + g);
    *(int4*)&Qs[row * QS_STRIDE + c8 * 8] = q;
    *(int4*)&Ks[row * QS_STRIDE + c8 * 8] = k;
    union { int4 i4; ush u[8]; } vu; vu.i4 = v;
#pragma unroll
    for (int dd = 0; dd < 8; dd++)
      Vt[vt_idx(c8 * 8 + dd, row)] = vu.u[dd];
  }
  __syncthreads();

  const int lane = t & 63, wv = t >> 6;
  const int col = lane & 15, quad = lane >> 4;
  const int m0 = wv * 32;  // wave owns rows m0..m0+31, all 128 cols
  const f32x4 z4 = {0.f, 0.f, 0.f, 0.f};

  // ---- S = Q K^T : 2 m-tiles x 8 n-tiles x 2 k-steps ----
  f32x4 sacc[2][8];
#pragma unroll
  for (int i = 0; i < 2; i++)
#pragma unroll
    for (int j = 0; j < 8; j++) sacc[i][j] = z4;
#pragma unroll
  for (int k0 = 0; k0 < 64; k0 += 32) {
    bf16x8 a[2], kb[8];
#pragma unroll
    for (int i = 0; i < 2; i++)
      a[i] = bc8(*(const int4*)&Qs[(m0 + i * 16 + col) * QS_STRIDE + k0 + quad * 8]);
#pragma unroll
    for (int j = 0; j < 8; j++)
      kb[j] = bc8(*(const int4*)&Ks[(j * 16 + col) * QS_STRIDE + k0 + quad * 8]);
#pragma unroll
    for (int i = 0; i < 2; i++)
#pragma unroll
      for (int j = 0; j < 8; j++)
        sacc[i][j] = __builtin_amdgcn_mfma_f32_16x16x32_bf16(a[i], kb[j], sacc[i][j], 0, 0, 0);
  }

  // ---- softmax (faithful: clip +-(1-eps), /8, exp, sum, clip [eps,1-eps]) ----
  const float CLIP = 1.0f - 1e-7f;
  float e[2][8][4], inv[2][4];
#pragma unroll
  for (int i = 0; i < 2; i++)
#pragma unroll
    for (int r = 0; r < 4; r++) {
      float part = 0.f;
#pragma unroll
      for (int j = 0; j < 8; j++) {
        float s = sacc[i][j][r];
        s = fminf(fmaxf(s, -CLIP), CLIP) * 0.125f;
        const float ee = __expf(s);
        e[i][j][r] = ee;
        part += ee;
      }
      part += __shfl_xor(part, 1);
      part += __shfl_xor(part, 2);
      part += __shfl_xor(part, 4);
      part += __shfl_xor(part, 8);
      inv[i][r] = 1.0f / part;
    }
  __syncthreads();  // barrier1: all Qs/Ks reads complete -> safe to overlay P

  // lane's rows: m0 + 16i + 4*quad + r; cols: 16j + col (C/D layout, m89)
#pragma unroll
  for (int i = 0; i < 2; i++)
#pragma unroll
    for (int r = 0; r < 4; r++) {
      const int row = m0 + i * 16 + quad * 4 + r;
#pragma unroll
      for (int j = 0; j < 8; j++) {
        const float pv = fminf(fmaxf(e[i][j][r] * inv[i][r], 1e-7f), CLIP);
        P[row * P_STRIDE + j * 16 + col] = f2b(pv);
      }
    }
  __syncthreads();  // barrier2: P complete

  // ---- xv = P V : 2 m-tiles x 4 n-tiles x 4 k-steps ----
  f32x4 oacc[2][4];
#pragma unroll
  for (int i = 0; i < 2; i++)
#pragma unroll
    for (int j = 0; j < 4; j++) oacc[i][j] = z4;
#pragma unroll
  for (int k0 = 0; k0 < 128; k0 += 32) {
    bf16x8 a[2], vb[4];
#pragma unroll
    for (int i = 0; i < 2; i++)
      a[i] = bc8(*(const int4*)&P[(m0 + i * 16 + col) * P_STRIDE + k0 + quad * 8]);
#pragma unroll
    for (int j = 0; j < 4; j++)
      vb[j] = bc8(*(const int4*)&Vt[vt_idx(j * 16 + col, k0 + quad * 8)]);
#pragma unroll
    for (int i = 0; i < 2; i++)
#pragma unroll
      for (int j = 0; j < 4; j++)
        oacc[i][j] = __builtin_amdgcn_mfma_f32_16x16x32_bf16(a[i], vb[j], oacc[i][j], 0, 0, 0);
  }

  // ---- epilogue ----
#pragma unroll
  for (int i = 0; i < 2; i++)
#pragma unroll
    for (int r = 0; r < 4; r++) {
      const int row = m0 + i * 16 + quad * 4 + r;
#pragma unroll
      for (int j = 0; j < 4; j++) {
        const int d = j * 16 + col;
        const float val = oacc[i][j][r];
        if (PASS == 1) {
          Vb[base + (long)row * stride + d] = f2b(val);
        } else {
          const long oi = ((long)(b * 128 + pp) * 128 + row) * 512 + d * 8 + n;
          if (flg) ((ush*)outp)[oi] = f2b(val);
          else     ((float*)outp)[oi] = val;
        }
      }
    }
}

// ---------- host ----------
extern "C" void kernel_launch(void* const* d_in, const int* in_sizes, int n_in,
                              void* d_out, int out_size, void* d_ws, size_t ws_size,
                              hipStream_t stream) {
  const void* x  = d_in[0];
  const void* wq = d_in[1];
  const void* bq = d_in[2];
  const void* wk = d_in[3];
  const void* bk = d_in[4];
  const void* wv = d_in[5];
  const void* bv = d_in[6];

  char* ws = (char*)d_ws;
  int*   flag  = (int*)ws;                       // @0
  float* biasf = (float*)(ws + 256);             // 3*512 fp32
  ush*   wTb   = (ush*)(ws + 8192);              // 1.5 MB
  ush*   xb    = (ush*)(ws + 8192 + 1572864);    // 64 MB
  ush*   qkv   = (ush*)(ws + 8192 + 1572864 + 67108864);  // 3*64 MB bf16

  dim3 blk(256);
  detect_dtype<<<1, blk, 0, stream>>>((const ush*)x, flag);
  pack_bias<<<3, 512, 0, stream>>>(bq, bk, bv, biasf, flag);
  pack_w<<<dim3(16, 16, 3), blk, 0, stream>>>(wq, wk, wv, wTb, flag);
  pack_x<<<16384, blk, 0, stream>>>(x, xb, flag);

  ush* Q = qkv;
  ush* K = Q + NE;
  ush* V = K + NE;
  proj_gemm<<<dim3(4, 512, 3), blk, 0, stream>>>(xb, wTb, biasf, Q);
  dim3 agrid(128, 8, 4);
  axial_attn_mfma<1><<<agrid, blk, 0, stream>>>(Q, K, V, d_out, flag);
  axial_attn_mfma<2><<<agrid, blk, 0, stream>>>(Q, K, V, d_out, flag);
}